// Round 3
// baseline (121.881 us; speedup 1.0000x reference)
//
#include <hip/hip_runtime.h>

// Problem constants: B=1024, F=33, D=128, A=128, P=F*(F-1)/2=528
#define FN 33
#define DN 128
#define AN 128
#define PN 528
#define XS 136     // fp16 row stride for xh in LDS (272 B, 16B-aligned, non-pow2)
#define TS 36      // float row stride for attn2d (144 B)

typedef __attribute__((ext_vector_type(8))) _Float16 half8;
typedef __attribute__((ext_vector_type(4))) float f32x4;
typedef __attribute__((ext_vector_type(4))) unsigned int u32x4;

__device__ __forceinline__ unsigned int pkrtz(float a, float b) {
  return __builtin_bit_cast(unsigned int, __builtin_amdgcn_cvt_pkrtz(a, b));
}

// sum over the 16-lane DPP row via row_ror rotations (VALU pipe, no LDS)
__device__ __forceinline__ float row_sum16(float v) {
  v += __builtin_bit_cast(float, __builtin_amdgcn_update_dpp(0, __builtin_bit_cast(int, v), 0x128, 0xF, 0xF, false));
  v += __builtin_bit_cast(float, __builtin_amdgcn_update_dpp(0, __builtin_bit_cast(int, v), 0x124, 0xF, 0xF, false));
  v += __builtin_bit_cast(float, __builtin_amdgcn_update_dpp(0, __builtin_bit_cast(int, v), 0x122, 0xF, 0xF, false));
  v += __builtin_bit_cast(float, __builtin_amdgcn_update_dpp(0, __builtin_bit_cast(int, v), 0x121, 0xF, 0xF, false));
  return v;
}

// R3: critical-path (latency) attack. 512 threads / 8 waves per block,
// 2-D split wave = mq*2+nh: each wave owns only 8-9 m-tiles (vs 17 in R1,
// 33 in R2) x 64 output cols. Every barrier-to-barrier serial chain
// (staging, tile walk, softmax, epilogue) shrinks ~2x; LDS traffic back to
// R1 level. Same total MFMA work.
__global__ __launch_bounds__(512, 4)
void afm_kernel(const float* __restrict__ gnn, const float* __restrict__ xg,
                const float* __restrict__ Wg,  const float* __restrict__ bg,
                float* __restrict__ out)
{
  __shared__ __align__(16) _Float16 xh[FN * XS];        // 8976 B, x[b] as fp16
  __shared__ __align__(16) float attn2d[FN * TS];       // 4752 B, unnormalized exp
  __shared__ __align__(16) float sp[2][PN];             // 4224 B, per-nh score partials
  __shared__ __align__(16) float part[512];             // epilogue partials
  __shared__ unsigned short rowcol[PN];                 // i | (j<<8)
  __shared__ float red[16];

  const int tid  = threadIdx.x;
  const int b    = blockIdx.x;
  const int wave = tid >> 6;
  const int lane = tid & 63;
  const int q    = lane >> 4;   // quad 0..3
  const int u    = lane & 15;
  const int nh   = wave & 1;    // n-half: columns [nh*64, nh*64+64)
  const int mq   = wave >> 1;   // m-quarter

  // ---------------- W half: global -> registers (fp16), issued early --------
  // Bf[nn][kk]: lane holds W[a = nh*64 + nn*16 + u][k = kk*32 + q*8 .. +8]
  half8 Bf[4][4];
  float garr[4], barr[4];
  #pragma unroll
  for (int nn = 0; nn < 4; nn++) {
    const int a = nh * 64 + nn * 16 + u;
    const float* src = Wg + (size_t)a * DN + q * 8;
    #pragma unroll
    for (int kk = 0; kk < 4; kk++) {
      f32x4 w0 = *(const f32x4*)(src + kk * 32);
      f32x4 w1 = *(const f32x4*)(src + kk * 32 + 4);
      u32x4 pk;
      pk.x = pkrtz(w0.x, w0.y);
      pk.y = pkrtz(w0.z, w0.w);
      pk.z = pkrtz(w1.x, w1.y);
      pk.w = pkrtz(w1.z, w1.w);
      Bf[nn][kk] = __builtin_bit_cast(half8, pk);
      asm volatile("" : "+v"(Bf[nn][kk]));   // pin: forbid remat/sinking
    }
    garr[nn] = gnn[(size_t)b * AN + a];
    barr[nn] = bg[a];
    asm volatile("" : "+v"(garr[nn]), "+v"(barr[nn]));
  }

  // ---------------- staging (x -> fp16 LDS, pair table, attn2d zero) --------
  for (int idx = tid; idx < FN * TS; idx += 512) attn2d[idx] = 0.0f;

  const f32x4* xg4 = (const f32x4*)(xg + (size_t)b * FN * DN);
  for (int idx = tid; idx < (FN * DN) / 4; idx += 512) {   // 1056 float4, ~2/thread
    f32x4 v = xg4[idx];
    int i  = idx >> 5;           // field row
    int d0 = (idx & 31) << 2;
    *(uint2*)&xh[i * XS + d0] = make_uint2(pkrtz(v.x, v.y), pkrtz(v.z, v.w));
  }
  for (int p = tid; p < PN; p += 512) {
    int i = 0, rem = p;
    while (rem >= FN - 1 - i) { rem -= FN - 1 - i; i++; }
    rowcol[p] = (unsigned short)(i | ((i + 1 + rem) << 8));
  }
  __syncthreads();

  // ---------------- fm matmul + score partials (8-9 tiles per wave) ---------
  // mq tile ranges: [0,9) [9,17) [17,25) [25,33)
  const int t_beg = (mq == 0) ? 0 : (mq * 8 + 1);
  const int t_end = (mq + 1) * 8 + 1;
  unsigned int rc_next = rowcol[t_beg * 16 + u];
  for (int t = t_beg; t < t_end; ++t) {
    const unsigned int rc = rc_next;
    if (t + 1 < t_end) rc_next = rowcol[(t + 1) * 16 + u];
    const int r = rc & 255, c = rc >> 8;
    const _Float16* xr_base = &xh[r * XS + q * 8];
    const _Float16* xc_base = &xh[c * XS + q * 8];

    f32x4 acc[4];
    #pragma unroll
    for (int nn = 0; nn < 4; nn++) acc[nn] = (f32x4){0.f, 0.f, 0.f, 0.f};

    __builtin_amdgcn_s_setprio(1);
    #pragma unroll
    for (int kk = 0; kk < 4; kk++) {
      half8 af = *(const half8*)(xr_base + kk * 32) * *(const half8*)(xc_base + kk * 32);
      #pragma unroll
      for (int nn = 0; nn < 4; nn++)
        acc[nn] = __builtin_amdgcn_mfma_f32_16x16x32_f16(af, Bf[nn][kk], acc[nn], 0, 0, 0);
    }
    __builtin_amdgcn_s_setprio(0);

    // fused bias + relu + gnn dot: D[row=q*4+rr][col=u], a = nh*64+nn*16+u
    float sc[4] = {0.f, 0.f, 0.f, 0.f};
    #pragma unroll
    for (int nn = 0; nn < 4; nn++)
      #pragma unroll
      for (int rr = 0; rr < 4; rr++)
        sc[rr] = fmaf(fmaxf(acc[nn][rr] + barr[nn], 0.f), garr[nn], sc[rr]);
    #pragma unroll
    for (int rr = 0; rr < 4; rr++) sc[rr] = row_sum16(sc[rr]);
    if (u == 0)
      *(f32x4*)&sp[nh][t * 16 + q * 4] = (f32x4){sc[0], sc[1], sc[2], sc[3]};
  }
  __syncthreads();

  // ---------------- softmax over 528 scores (<=2 per thread) ----------------
  float s0 = sp[0][tid] + sp[1][tid];
  float s1 = (tid < 16) ? (sp[0][tid + 512] + sp[1][tid + 512]) : -3.4e38f;
  float m = fmaxf(s0, s1);
  #pragma unroll
  for (int off = 32; off >= 1; off >>= 1) m = fmaxf(m, __shfl_xor(m, off, 64));
  if (lane == 0) red[wave] = m;
  __syncthreads();
  float smax = red[0];
  #pragma unroll
  for (int w = 1; w < 8; w++) smax = fmaxf(smax, red[w]);

  float e0 = __expf(s0 - smax);
  float e1 = (tid < 16) ? __expf(s1 - smax) : 0.f;
  {
    unsigned int rc = rowcol[tid];
    attn2d[(rc & 255) * TS + ((rc >> 8) - (rc & 255) - 1)] = e0;
    if (tid < 16) {
      rc = rowcol[tid + 512];
      attn2d[(rc & 255) * TS + ((rc >> 8) - (rc & 255) - 1)] = e1;
    }
  }
  float lsum = e0 + e1;
  #pragma unroll
  for (int off = 32; off >= 1; off >>= 1) lsum += __shfl_xor(lsum, off, 64);
  if (lane == 0) red[8 + wave] = lsum;
  __syncthreads();
  float Z = red[8];
  #pragma unroll
  for (int w = 1; w < 8; w++) Z += red[8 + w];

  // ---------------- epilogue: out = [gnn, 100 * attn @ inner] ---------------
  // 4-way i-split by residue (i % 4 == g): FMA counts 144/136/128/120 per
  // group, balanced. i stays compile-time so xcol[] is statically indexed.
  {
    const int d = tid & 127;
    const int g = (tid >> 7) & 3;    // residue group (wave-uniform)
    float xcol[36];
    #pragma unroll
    for (int i = 0; i < FN; i++) xcol[i] = (float)xh[i * XS + d];
    xcol[33] = 0.f; xcol[34] = 0.f; xcol[35] = 0.f;

    float acc = 0.f;
    #pragma unroll
    for (int i = 0; i < 33; i++) {
      if ((i & 3) != g) continue;
      const int L = FN - 1 - i;                  // pairs (i, i+1+jj), jj < L
      const int nf4 = (L + 3) >> 2;
      float ti = 0.f;
      #pragma unroll
      for (int t = 0; t < nf4; t++) {
        f32x4 a4 = *(const f32x4*)&attn2d[i * TS + t * 4];  // pad entries are 0
        ti = fmaf(a4.x, xcol[i + 1 + t * 4 + 0], ti);
        ti = fmaf(a4.y, xcol[i + 1 + t * 4 + 1], ti);
        ti = fmaf(a4.z, xcol[i + 1 + t * 4 + 2], ti);
        ti = fmaf(a4.w, xcol[i + 1 + t * 4 + 3], ti);
      }
      acc = fmaf(xcol[i], ti, acc);
    }
    part[tid] = acc;
  }
  __syncthreads();
  if (tid < DN) {
    float tot = (part[tid] + part[tid + 128]) + (part[tid + 256] + part[tid + 384]);
    out[(size_t)b * (AN + DN) + AN + tid] = tot * (100.0f / Z);
  } else if (tid < 256) {
    const int a = tid - 128;
    out[(size_t)b * (AN + DN) + a] = gnn[(size_t)b * AN + a];
  }
}

extern "C" void kernel_launch(void* const* d_in, const int* in_sizes, int n_in,
                              void* d_out, int out_size, void* d_ws, size_t ws_size,
                              hipStream_t stream) {
  (void)n_in; (void)out_size; (void)d_ws; (void)ws_size;
  const float* gnn  = (const float*)d_in[0];
  const float* x    = (const float*)d_in[1];
  const float* W    = (const float*)d_in[2];
  const float* bias = (const float*)d_in[3];
  float* out = (float*)d_out;
  const int Bn = in_sizes[0] / AN;   // 1024
  afm_kernel<<<dim3(Bn), dim3(512), 0, stream>>>(gnn, x, W, bias, out);
}

// Round 4
// 106.877 us; speedup vs baseline: 1.1404x; 1.1404x over previous
//
#include <hip/hip_runtime.h>

// Problem constants: B=1024, F=33, D=128, A=128, P=F*(F-1)/2=528
#define FN 33
#define DN 128
#define AN 128
#define PN 528
#define XS 136     // fp16 row stride for xh in LDS (272 B, 16B-aligned, non-pow2)
#define TS 36      // float row stride for attn2d (144 B)

typedef __attribute__((ext_vector_type(8))) _Float16 half8;
typedef __attribute__((ext_vector_type(4))) float f32x4;
typedef __attribute__((ext_vector_type(4))) unsigned int u32x4;

__device__ __forceinline__ unsigned int pkrtz(float a, float b) {
  return __builtin_bit_cast(unsigned int, __builtin_amdgcn_cvt_pkrtz(a, b));
}

// sum over the 16-lane DPP row via row_ror rotations (VALU pipe, no LDS)
__device__ __forceinline__ float row_sum16(float v) {
  v += __builtin_bit_cast(float, __builtin_amdgcn_update_dpp(0, __builtin_bit_cast(int, v), 0x128, 0xF, 0xF, false));
  v += __builtin_bit_cast(float, __builtin_amdgcn_update_dpp(0, __builtin_bit_cast(int, v), 0x124, 0xF, 0xF, false));
  v += __builtin_bit_cast(float, __builtin_amdgcn_update_dpp(0, __builtin_bit_cast(int, v), 0x122, 0xF, 0xF, false));
  v += __builtin_bit_cast(float, __builtin_amdgcn_update_dpp(0, __builtin_bit_cast(int, v), 0x121, 0xF, 0xF, false));
  return v;
}

// Per-batch MFMA walk: waves split (mh x nh); 17/16 tiles x 64 cols each.
// Macro (not lambda) so GB indexes a named register array statically (rule #20).
#define WALK(XHB, GB, SPB)                                                    \
  {                                                                           \
    const int t_beg = mh ? 17 : 0;                                            \
    const int t_end = mh ? 33 : 17;                                           \
    unsigned int rc_next = rowcol[t_beg * 16 + u];                            \
    for (int t = t_beg; t < t_end; ++t) {                                     \
      const unsigned int rc = rc_next;                                        \
      if (t + 1 < t_end) rc_next = rowcol[(t + 1) * 16 + u];                  \
      const int r = rc & 255, c = rc >> 8;                                    \
      const _Float16* xr_base = &XHB[r * XS + q * 8];                         \
      const _Float16* xc_base = &XHB[c * XS + q * 8];                         \
      f32x4 acc[4];                                                           \
      _Pragma("unroll")                                                       \
      for (int nn = 0; nn < 4; nn++) acc[nn] = (f32x4){0.f, 0.f, 0.f, 0.f};   \
      __builtin_amdgcn_s_setprio(1);                                          \
      _Pragma("unroll")                                                       \
      for (int kk = 0; kk < 4; kk++) {                                        \
        half8 af = *(const half8*)(xr_base + kk * 32) *                       \
                   *(const half8*)(xc_base + kk * 32);                        \
        _Pragma("unroll")                                                     \
        for (int nn = 0; nn < 4; nn++)                                        \
          acc[nn] = __builtin_amdgcn_mfma_f32_16x16x32_f16(af, Bf[nn][kk],    \
                                                           acc[nn], 0, 0, 0);  \
      }                                                                       \
      __builtin_amdgcn_s_setprio(0);                                          \
      float sc[4] = {0.f, 0.f, 0.f, 0.f};                                     \
      _Pragma("unroll")                                                       \
      for (int nn = 0; nn < 4; nn++)                                          \
        _Pragma("unroll")                                                     \
        for (int rr = 0; rr < 4; rr++)                                        \
          sc[rr] = fmaf(fmaxf(acc[nn][rr] + barr[nn], 0.f), GB[nn], sc[rr]);  \
      _Pragma("unroll")                                                       \
      for (int rr = 0; rr < 4; rr++) sc[rr] = row_sum16(sc[rr]);              \
      if (u == 0)                                                             \
        *(f32x4*)&SPB[t * 16 + q * 4] = (f32x4){sc[0], sc[1], sc[2], sc[3]};  \
    }                                                                         \
  }

// Epilogue partial: part[tid] = sum over this thread's i-parity of
// x[i][d] * (sum_j e[i][j] x[j][d]).  Static xcol indexing throughout.
#define EPI(A2D, XHB)                                                         \
  {                                                                           \
    const int d = tid & 127;                                                  \
    const int h = tid >> 7;                                                   \
    float xcol[36];                                                           \
    _Pragma("unroll")                                                         \
    for (int i = 0; i < FN; i++) xcol[i] = (float)XHB[i * XS + d];            \
    xcol[33] = 0.f; xcol[34] = 0.f; xcol[35] = 0.f;                           \
    float accv = 0.f;                                                         \
    _Pragma("unroll")                                                         \
    for (int i = 0; i < 32; i++) {                                            \
      if ((i & 1) != h) continue;                                             \
      const int L = FN - 1 - i;                                               \
      const int nf4 = (L + 3) >> 2;                                           \
      float ti = 0.f;                                                         \
      _Pragma("unroll")                                                       \
      for (int t = 0; t < nf4; t++) {                                         \
        f32x4 a4 = *(const f32x4*)&A2D[i * TS + t * 4];                       \
        ti = fmaf(a4.x, xcol[i + 1 + t * 4 + 0], ti);                         \
        ti = fmaf(a4.y, xcol[i + 1 + t * 4 + 1], ti);                         \
        ti = fmaf(a4.z, xcol[i + 1 + t * 4 + 2], ti);                         \
        ti = fmaf(a4.w, xcol[i + 1 + t * 4 + 3], ti);                         \
      }                                                                       \
      accv = fmaf(xcol[i], ti, accv);                                         \
    }                                                                         \
    part[tid] = accv;                                                         \
  }

// R4: batch fusion BPB=2. Grid 512, 256 thr. One staging wait + one W fetch
// per 2 batches; epilogue(b0)+out(b0) hidden in walk(b1)'s shadow; 8 barriers
// per 2 batches (was 10).
__global__ __launch_bounds__(256, 2)
void afm_kernel(const float* __restrict__ gnn, const float* __restrict__ xg,
                const float* __restrict__ Wg,  const float* __restrict__ bg,
                float* __restrict__ out)
{
  __shared__ __align__(16) _Float16 xh[2][FN * XS];     // 17.9 KB
  __shared__ __align__(16) float attn2d[2][FN * TS];    // 9.5 KB
  __shared__ __align__(16) float sp[2][2][PN];          // 8.4 KB [bi][nh][p]
  __shared__ __align__(16) float part[256];             // 1 KB
  __shared__ unsigned short rowcol[PN];                 // 1 KB
  __shared__ float red[16];

  const int tid  = threadIdx.x;
  const int b0   = blockIdx.x * 2;
  const int b1   = b0 + 1;
  const int wave = tid >> 6;
  const int lane = tid & 63;
  const int q    = lane >> 4;   // quad 0..3
  const int u    = lane & 15;
  const int nh   = wave & 1;    // n-half: cols [nh*64, nh*64+64)
  const int mh   = wave >> 1;   // m-half: tiles [0,17) / [17,33)

  // -------- x loads for BOTH batches issued first (160 B/thread in flight) --
  const f32x4* xb0 = (const f32x4*)(xg + (size_t)b0 * FN * DN);
  const f32x4* xb1 = (const f32x4*)(xg + (size_t)b1 * FN * DN);
  f32x4 xv0[4], xv1[4], xt0 = {0,0,0,0}, xt1 = {0,0,0,0};
  #pragma unroll
  for (int s = 0; s < 4; s++) xv0[s] = xb0[tid + s * 256];
  #pragma unroll
  for (int s = 0; s < 4; s++) xv1[s] = xb1[tid + s * 256];
  const bool tail = tid < 32;          // 1056 = 4*256 + 32
  if (tail) { xt0 = xb0[1024 + tid]; xt1 = xb1[1024 + tid]; }

  // -------- W quadrant -> Bf regs (once per 2 batches); gnn x2; bias --------
  half8 Bf[4][4];
  float g0[4], g1[4], barr[4];
  #pragma unroll
  for (int nn = 0; nn < 4; nn++) {
    const int a = nh * 64 + nn * 16 + u;
    const float* src = Wg + (size_t)a * DN + q * 8;
    #pragma unroll
    for (int kk = 0; kk < 4; kk++) {
      f32x4 w0 = *(const f32x4*)(src + kk * 32);
      f32x4 w1 = *(const f32x4*)(src + kk * 32 + 4);
      u32x4 pk;
      pk.x = pkrtz(w0.x, w0.y);
      pk.y = pkrtz(w0.z, w0.w);
      pk.z = pkrtz(w1.x, w1.y);
      pk.w = pkrtz(w1.z, w1.w);
      Bf[nn][kk] = __builtin_bit_cast(half8, pk);
      asm volatile("" : "+v"(Bf[nn][kk]));   // pin: forbid remat/sinking
    }
    g0[nn] = gnn[(size_t)b0 * AN + a];
    g1[nn] = gnn[(size_t)b1 * AN + a];
    barr[nn] = bg[a];
    asm volatile("" : "+v"(g0[nn]), "+v"(g1[nn]), "+v"(barr[nn]));
  }

  // -------- VALU-only staging overlapped with load flight -------------------
  {
    float* a2z = &attn2d[0][0];
    for (int idx = tid; idx < 2 * FN * TS; idx += 256) a2z[idx] = 0.0f;
    for (int p = tid; p < PN; p += 256) {
      int i = 0, rem = p;
      while (rem >= FN - 1 - i) { rem -= FN - 1 - i; i++; }
      rowcol[p] = (unsigned short)(i | ((i + 1 + rem) << 8));
    }
  }

  // -------- convert + store x (both batches) --------------------------------
  #pragma unroll
  for (int s = 0; s < 4; s++) {
    const int idx = tid + s * 256;
    const int i = idx >> 5, d0 = (idx & 31) << 2;
    *(uint2*)&xh[0][i * XS + d0] = make_uint2(pkrtz(xv0[s].x, xv0[s].y), pkrtz(xv0[s].z, xv0[s].w));
    *(uint2*)&xh[1][i * XS + d0] = make_uint2(pkrtz(xv1[s].x, xv1[s].y), pkrtz(xv1[s].z, xv1[s].w));
  }
  if (tail) {
    const int idx = 1024 + tid;
    const int i = idx >> 5, d0 = (idx & 31) << 2;
    *(uint2*)&xh[0][i * XS + d0] = make_uint2(pkrtz(xt0.x, xt0.y), pkrtz(xt0.z, xt0.w));
    *(uint2*)&xh[1][i * XS + d0] = make_uint2(pkrtz(xt1.x, xt1.y), pkrtz(xt1.z, xt1.w));
  }
  __syncthreads();                                      // B1

  // -------- batch 0: walk --------------------------------------------------
  WALK(xh[0], g0, (&sp[0][nh][0]));
  __syncthreads();                                      // B2

  // -------- batch 0: softmax max-reduce ------------------------------------
  float s0a = sp[0][0][tid] + sp[0][1][tid];
  float s1a = sp[0][0][tid + 256] + sp[0][1][tid + 256];
  float s2a = (tid < 16) ? (sp[0][0][tid + 512] + sp[0][1][tid + 512]) : -3.4e38f;
  {
    float m = fmaxf(fmaxf(s0a, s1a), s2a);
    #pragma unroll
    for (int off = 32; off >= 1; off >>= 1) m = fmaxf(m, __shfl_xor(m, off, 64));
    if (lane == 0) red[wave] = m;
  }
  __syncthreads();                                      // B3

  // -------- batch 0: exp + scatter + sum-reduce ----------------------------
  const float smax0 = fmaxf(fmaxf(red[0], red[1]), fmaxf(red[2], red[3]));
  {
    float e0 = __expf(s0a - smax0);
    float e1 = __expf(s1a - smax0);
    float e2 = (tid < 16) ? __expf(s2a - smax0) : 0.f;
    unsigned int rc = rowcol[tid];
    attn2d[0][(rc & 255) * TS + ((rc >> 8) - (rc & 255) - 1)] = e0;
    rc = rowcol[tid + 256];
    attn2d[0][(rc & 255) * TS + ((rc >> 8) - (rc & 255) - 1)] = e1;
    if (tid < 16) {
      rc = rowcol[tid + 512];
      attn2d[0][(rc & 255) * TS + ((rc >> 8) - (rc & 255) - 1)] = e2;
    }
    float lsum = e0 + e1 + e2;
    #pragma unroll
    for (int off = 32; off >= 1; off >>= 1) lsum += __shfl_xor(lsum, off, 64);
    if (lane == 0) red[4 + wave] = lsum;
  }
  __syncthreads();                                      // B4
  const float Z0 = (red[4] + red[5]) + (red[6] + red[7]);

  // -------- walk(b1) with epi(b0) in its shadow (no barrier between) -------
  WALK(xh[1], g1, (&sp[1][nh][0]));
  EPI(attn2d[0], xh[0]);
  __syncthreads();                                      // B5

  // -------- out(b0) + batch 1 max-reduce -----------------------------------
  float s0b = sp[1][0][tid] + sp[1][1][tid];
  float s1b = sp[1][0][tid + 256] + sp[1][1][tid + 256];
  float s2b = (tid < 16) ? (sp[1][0][tid + 512] + sp[1][1][tid + 512]) : -3.4e38f;
  {
    float m = fmaxf(fmaxf(s0b, s1b), s2b);
    #pragma unroll
    for (int off = 32; off >= 1; off >>= 1) m = fmaxf(m, __shfl_xor(m, off, 64));
    if (lane == 0) red[8 + wave] = m;
  }
  if (tid < DN) {
    float tot = part[tid] + part[tid + 128];
    out[(size_t)b0 * (AN + DN) + AN + tid] = tot * (100.0f / Z0);
  } else {
    const int a = tid - 128;
    out[(size_t)b0 * (AN + DN) + a] = gnn[(size_t)b0 * AN + a];
  }
  __syncthreads();                                      // B6

  // -------- batch 1: exp + scatter + sum-reduce ----------------------------
  const float smax1 = fmaxf(fmaxf(red[8], red[9]), fmaxf(red[10], red[11]));
  {
    float e0 = __expf(s0b - smax1);
    float e1 = __expf(s1b - smax1);
    float e2 = (tid < 16) ? __expf(s2b - smax1) : 0.f;
    unsigned int rc = rowcol[tid];
    attn2d[1][(rc & 255) * TS + ((rc >> 8) - (rc & 255) - 1)] = e0;
    rc = rowcol[tid + 256];
    attn2d[1][(rc & 255) * TS + ((rc >> 8) - (rc & 255) - 1)] = e1;
    if (tid < 16) {
      rc = rowcol[tid + 512];
      attn2d[1][(rc & 255) * TS + ((rc >> 8) - (rc & 255) - 1)] = e2;
    }
    float lsum = e0 + e1 + e2;
    #pragma unroll
    for (int off = 32; off >= 1; off >>= 1) lsum += __shfl_xor(lsum, off, 64);
    if (lane == 0) red[12 + wave] = lsum;
  }
  __syncthreads();                                      // B7
  const float Z1 = (red[12] + red[13]) + (red[14] + red[15]);

  // -------- batch 1: epilogue ----------------------------------------------
  EPI(attn2d[1], xh[1]);
  __syncthreads();                                      // B8

  if (tid < DN) {
    float tot = part[tid] + part[tid + 128];
    out[(size_t)b1 * (AN + DN) + AN + tid] = tot * (100.0f / Z1);
  } else {
    const int a = tid - 128;
    out[(size_t)b1 * (AN + DN) + a] = gnn[(size_t)b1 * AN + a];
  }
}

extern "C" void kernel_launch(void* const* d_in, const int* in_sizes, int n_in,
                              void* d_out, int out_size, void* d_ws, size_t ws_size,
                              hipStream_t stream) {
  (void)n_in; (void)out_size; (void)d_ws; (void)ws_size;
  const float* gnn  = (const float*)d_in[0];
  const float* x    = (const float*)d_in[1];
  const float* W    = (const float*)d_in[2];
  const float* bias = (const float*)d_in[3];
  float* out = (float*)d_out;
  const int Bn = in_sizes[0] / AN;   // 1024
  afm_kernel<<<dim3(Bn / 2), dim3(256), 0, stream>>>(gnn, x, W, bias, out);
}